// Round 1
// baseline (818.731 us; speedup 1.0000x reference)
//
#include <hip/hip_runtime.h>
#include <hip/hip_bf16.h>

// Problem constants (GroupGMM): B=8192, I=512, G=32, C=16, D=32, CD=512
#define BATCH 8192
#define IDIM  512
#define GDIM  32
#define NOUT  1040   // 16 (pi) + 512 (mu) + 512 (sigma)
#define NPAD  1152   // 9 * 128 tiles
#define KTOT  16416  // G*I + G bias rows
#define BK    32

typedef short bf16x8 __attribute__((ext_vector_type(8)));   // 8 bf16 (4 VGPRs)
typedef float floatx4 __attribute__((ext_vector_type(4)));  // MFMA acc

#define GLP(p)  (const __attribute__((address_space(1))) void*)(p)
#define LDSP(p) (__attribute__((address_space(3))) void*)(p)

__device__ inline unsigned pk2(float a, float b) {
    union { __hip_bfloat162 h2; unsigned u; } cv;
    cv.h2 = __float22bfloat162_rn(float2{a, b});
    return cv.u;
}

// ---------------- prep: Wt[n][k] bf16, n-major, bias folded as k in [16384,16416) ----
__global__ void prep_wt(const float* __restrict__ Wmu, const float* __restrict__ bmu,
                        const float* __restrict__ Wsig, const float* __restrict__ bsig,
                        const float* __restrict__ Wpi, const float* __restrict__ bpi,
                        unsigned short* __restrict__ Wt) {
    int n = blockIdx.y * 256 + threadIdx.x;
    if (n >= NPAD) return;
    int k0 = blockIdx.x * 8;
    float v[8];
#pragma unroll
    for (int j = 0; j < 8; ++j) {
        int k = k0 + j;
        float val = 0.0f;
        if (n < NOUT) {
            if (k < GDIM * IDIM) {
                int gg = k >> 9, i = k & 511;
                if (n < 16)        val = Wpi [(gg * 512 + i) * 16  + n];
                else if (n < 528)  val = Wmu [(gg * 512 + i) * 512 + (n - 16)];
                else               val = Wsig[(gg * 512 + i) * 512 + (n - 528)];
            } else {
                int gg = k - GDIM * IDIM;
                if (n < 16)        val = bpi [gg * 16  + n];
                else if (n < 528)  val = bmu [gg * 512 + (n - 16)];
                else               val = bsig[gg * 512 + (n - 528)];
            }
        }
        v[j] = val;
    }
    uint4 p;
    p.x = pk2(v[0], v[1]); p.y = pk2(v[2], v[3]);
    p.z = pk2(v[4], v[5]); p.w = pk2(v[6], v[7]);
    *(uint4*)&Wt[(size_t)n * KTOT + k0] = p;
}

// ---------------- GEMM: out[b,n] = A[b,:] @ Wt[:,n], A generated on the fly ---------
__global__ __launch_bounds__(256) void gemm_gmm(
        const float* __restrict__ x, const float* __restrict__ g,
        const unsigned short* __restrict__ Wt, float* __restrict__ out) {
    __shared__ __align__(16) unsigned short lds_a[128 * BK];  // [m][k] 8KB
    __shared__ __align__(16) unsigned short lds_b[128 * BK];  // [n][k] 8KB

    const int t    = threadIdx.x;
    const int lane = t & 63;
    const int w    = t >> 6;
    const int wm   = (w & 1) * 64;
    const int wn   = (w >> 1) * 64;
    const int q    = lane >> 4;
    const int l15  = lane & 15;

    const int m0 = blockIdx.x * 128;
    const int n0 = blockIdx.y * 128;

    floatx4 acc[4][4] = {};

    // A staging: thread t handles row (t>>1), 16 k-elems at half (t&1)
    const int arow  = t >> 1;
    const int ahalf = t & 1;
    const float* xrow = x + (size_t)(m0 + arow) * IDIM + ahalf * 16;
    const float* grow = g + (size_t)(m0 + arow) * GDIM;

    // B staging: two 16B DMA chunks per thread; chunk c: flat = t + 256c
    const unsigned short* WtB0 = Wt + (size_t)(n0 + (t >> 2)) * KTOT + (t & 3) * 8;
    const unsigned short* WtB1 = Wt + (size_t)(n0 + 64 + (t >> 2)) * KTOT + (t & 3) * 8;
    unsigned short* ldsB0 = lds_b + t * 8;
    unsigned short* ldsB1 = lds_b + (t + 256) * 8;

    for (int k0 = 0; k0 < KTOT; k0 += BK) {
        __syncthreads();
        // ---- B tile: global -> LDS DMA, 16B/lane ----
        __builtin_amdgcn_global_load_lds(GLP(WtB0 + k0), LDSP(ldsB0), 16, 0, 0);
        __builtin_amdgcn_global_load_lds(GLP(WtB1 + k0), LDSP(ldsB1), 16, 0, 0);
        // ---- A tile: load fp32 x, scale by g[b, k0>>9], cvt bf16, LDS write ----
        const float4* src;
        float sc;
        if (k0 < GDIM * IDIM) {
            src = (const float4*)(xrow + (k0 & 511));
            sc  = grow[k0 >> 9];
        } else {                      // bias rows: A[b, 16384+j] = g[b, j]
            src = (const float4*)(grow + ahalf * 16);
            sc  = 1.0f;
        }
        float4 v0 = src[0], v1 = src[1], v2 = src[2], v3 = src[3];
        uint4 pa, pb;
        pa.x = pk2(v0.x * sc, v0.y * sc); pa.y = pk2(v0.z * sc, v0.w * sc);
        pa.z = pk2(v1.x * sc, v1.y * sc); pa.w = pk2(v1.z * sc, v1.w * sc);
        pb.x = pk2(v2.x * sc, v2.y * sc); pb.y = pk2(v2.z * sc, v2.w * sc);
        pb.z = pk2(v3.x * sc, v3.y * sc); pb.w = pk2(v3.z * sc, v3.w * sc);
        *(uint4*)&lds_a[arow * BK + ahalf * 16]     = pa;
        *(uint4*)&lds_a[arow * BK + ahalf * 16 + 8] = pb;
        __syncthreads();
        // ---- fragments + MFMA ----
        bf16x8 af[4], bfr[4];
#pragma unroll
        for (int tm = 0; tm < 4; ++tm)
            af[tm] = *(const bf16x8*)&lds_a[(wm + tm * 16 + l15) * BK + q * 8];
#pragma unroll
        for (int tn = 0; tn < 4; ++tn)
            bfr[tn] = *(const bf16x8*)&lds_b[(wn + tn * 16 + l15) * BK + q * 8];
#pragma unroll
        for (int tm = 0; tm < 4; ++tm)
#pragma unroll
            for (int tn = 0; tn < 4; ++tn)
                acc[tm][tn] = __builtin_amdgcn_mfma_f32_16x16x32_bf16(
                    af[tm], bfr[tn], acc[tm][tn], 0, 0, 0);
    }

    // ---- epilogue: softplus on sigma block, write only n < NOUT ----
#pragma unroll
    for (int tn = 0; tn < 4; ++tn) {
        int n = n0 + wn + tn * 16 + l15;
        if (n >= NOUT) continue;
        bool is_scale = (n >= 528);
#pragma unroll
        for (int tm = 0; tm < 4; ++tm) {
            int mbase = m0 + wm + tm * 16 + q * 4;
#pragma unroll
            for (int r = 0; r < 4; ++r) {
                float vv = acc[tm][tn][r];
                if (is_scale) {
                    float sp = (vv > 15.0f) ? vv : log1pf(expf(vv));
                    vv = sp + 1e-7f;
                }
                out[(size_t)(mbase + r) * NOUT + n] = vv;
            }
        }
    }
}

extern "C" void kernel_launch(void* const* d_in, const int* in_sizes, int n_in,
                              void* d_out, int out_size, void* d_ws, size_t ws_size,
                              hipStream_t stream) {
    const float* x    = (const float*)d_in[0];
    const float* g    = (const float*)d_in[1];
    const float* Wmu  = (const float*)d_in[2];
    const float* bmu  = (const float*)d_in[3];
    const float* Wsig = (const float*)d_in[4];
    const float* bsig = (const float*)d_in[5];
    const float* Wpi  = (const float*)d_in[6];
    const float* bpi  = (const float*)d_in[7];
    float* out = (float*)d_out;
    unsigned short* Wt = (unsigned short*)d_ws;  // needs NPAD*KTOT*2 = 37.8 MB

    prep_wt<<<dim3(KTOT / 8, 5), 256, 0, stream>>>(Wmu, bmu, Wsig, bsig, Wpi, bpi, Wt);
    gemm_gmm<<<dim3(BATCH / 128, NPAD / 128), 256, 0, stream>>>(x, g, Wt, out);
}

// Round 2
// 734.068 us; speedup vs baseline: 1.1153x; 1.1153x over previous
//
#include <hip/hip_runtime.h>
#include <hip/hip_bf16.h>

// Problem constants (GroupGMM): B=8192, I=512, G=32, C=16, D=32, CD=512
#define BATCH 8192
#define IDIM  512
#define GDIM  32
#define NOUT  1040   // 16 (pi) + 512 (mu) + 512 (sigma)
#define NPAD  1152   // 9 * 128 tiles
#define KTOT  16416  // G*I + G bias rows
#define BK    32
#define NSPLIT 4
#define KITERS 513   // KTOT/BK
#define APAD  40     // A-tile LDS row stride in shorts (32 + 8 pad -> conflict-free)

typedef short bf16x8 __attribute__((ext_vector_type(8)));   // 8 bf16 (4 VGPRs)
typedef float floatx4 __attribute__((ext_vector_type(4)));  // MFMA acc

#define GLP(p)  (const __attribute__((address_space(1))) void*)(p)
#define LDSP(p) (__attribute__((address_space(3))) void*)(p)

__device__ inline unsigned pk2(float a, float b) {
    union { __hip_bfloat162 h2; unsigned u; } cv;
    cv.h2 = __float22bfloat162_rn(float2{a, b});
    return cv.u;
}

// ---------------- prep: Wt[n][k] bf16, n-major, bias folded as k in [16384,16416) ----
__global__ void prep_wt(const float* __restrict__ Wmu, const float* __restrict__ bmu,
                        const float* __restrict__ Wsig, const float* __restrict__ bsig,
                        const float* __restrict__ Wpi, const float* __restrict__ bpi,
                        unsigned short* __restrict__ Wt) {
    int n = blockIdx.y * 256 + threadIdx.x;
    if (n >= NPAD) return;
    int k0 = blockIdx.x * 8;
    float v[8];
#pragma unroll
    for (int j = 0; j < 8; ++j) {
        int k = k0 + j;
        float val = 0.0f;
        if (n < NOUT) {
            if (k < GDIM * IDIM) {
                int gg = k >> 9, i = k & 511;
                if (n < 16)        val = Wpi [(gg * 512 + i) * 16  + n];
                else if (n < 528)  val = Wmu [(gg * 512 + i) * 512 + (n - 16)];
                else               val = Wsig[(gg * 512 + i) * 512 + (n - 528)];
            } else {
                int gg = k - GDIM * IDIM;
                if (n < 16)        val = bpi [gg * 16  + n];
                else if (n < 528)  val = bmu [gg * 512 + (n - 16)];
                else               val = bsig[gg * 512 + (n - 528)];
            }
        }
        v[j] = val;
    }
    uint4 p;
    p.x = pk2(v[0], v[1]); p.y = pk2(v[2], v[3]);
    p.z = pk2(v[4], v[5]); p.w = pk2(v[6], v[7]);
    *(uint4*)&Wt[(size_t)n * KTOT + k0] = p;
}

// ---------------- GEMM (split-K): acc[b,n] += A[b,kr] @ Wt[kr,n] -------------------
// A generated on the fly: A[b, g*512+i] = x[b,i]*g[b,g]; A[b,16384+j] = g[b,j].
__global__ __launch_bounds__(256) void gemm_gmm(
        const float* __restrict__ x, const float* __restrict__ g,
        const unsigned short* __restrict__ Wt, float* __restrict__ accbuf) {
    __shared__ __align__(16) unsigned short lds_a[128 * APAD];  // padded stride: no conflicts
    __shared__ __align__(16) unsigned short lds_b[128 * BK];    // XOR-swizzled chunk order

    const int t    = threadIdx.x;
    const int lane = t & 63;
    const int w    = t >> 6;
    const int wm   = (w & 1) * 64;
    const int wn   = (w >> 1) * 64;
    const int q    = lane >> 4;
    const int l15  = lane & 15;

    const int m0 = blockIdx.x * 128;
    const int n0 = blockIdx.y * 128;
    const int z  = blockIdx.z;
    const int it0 = (KITERS * z) / NSPLIT;
    const int it1 = (KITERS * (z + 1)) / NSPLIT;

    floatx4 acc[4][4] = {};

    // A staging: thread t handles row (t>>1), 16 k-elems at half (t&1)
    const int arow  = t >> 1;
    const int ahalf = t & 1;
    const float* xrow = x + (size_t)(m0 + arow) * IDIM + ahalf * 16;
    const float* grow = g + (size_t)(m0 + arow) * GDIM;

    // B staging: two 16B DMA chunks per thread. DMA scatters lane-contiguously
    // (slot = t, t+256); we XOR-swizzle WHICH global chunk each lane fetches so
    // that reads of (row, q) -> slot row*4 + (q ^ ((row>>1)&3)) are conflict-free.
    const int brow0 = t >> 2;
    const int bq0   = (t & 3) ^ ((t >> 3) & 3);
    const unsigned short* WtB0 = Wt + (size_t)(n0 + brow0) * KTOT + bq0 * 8;
    const unsigned short* WtB1 = Wt + (size_t)(n0 + 64 + brow0) * KTOT + bq0 * 8;
    unsigned short* ldsB0 = lds_b + t * 8;
    unsigned short* ldsB1 = lds_b + (t + 256) * 8;

    for (int it = it0; it < it1; ++it) {
        const int k0 = it * BK;
        __syncthreads();
        // ---- B tile: global -> LDS DMA, 16B/lane ----
        __builtin_amdgcn_global_load_lds(GLP(WtB0 + k0), LDSP(ldsB0), 16, 0, 0);
        __builtin_amdgcn_global_load_lds(GLP(WtB1 + k0), LDSP(ldsB1), 16, 0, 0);
        // ---- A tile: load fp32 x, scale by g[b, k0>>9], cvt bf16, LDS write ----
        const float4* src;
        float sc;
        if (k0 < GDIM * IDIM) {
            src = (const float4*)(xrow + (k0 & 511));
            sc  = grow[k0 >> 9];
        } else {                      // bias rows: A[b, 16384+j] = g[b, j]
            src = (const float4*)(grow + ahalf * 16);
            sc  = 1.0f;
        }
        float4 v0 = src[0], v1 = src[1], v2 = src[2], v3 = src[3];
        uint4 pa, pb;
        pa.x = pk2(v0.x * sc, v0.y * sc); pa.y = pk2(v0.z * sc, v0.w * sc);
        pa.z = pk2(v1.x * sc, v1.y * sc); pa.w = pk2(v1.z * sc, v1.w * sc);
        pb.x = pk2(v2.x * sc, v2.y * sc); pb.y = pk2(v2.z * sc, v2.w * sc);
        pb.z = pk2(v3.x * sc, v3.y * sc); pb.w = pk2(v3.z * sc, v3.w * sc);
        *(uint4*)&lds_a[arow * APAD + ahalf * 16]     = pa;
        *(uint4*)&lds_a[arow * APAD + ahalf * 16 + 8] = pb;
        __syncthreads();
        // ---- fragments + MFMA ----
        bf16x8 af[4], bfr[4];
#pragma unroll
        for (int tm = 0; tm < 4; ++tm)
            af[tm] = *(const bf16x8*)&lds_a[(wm + tm * 16 + l15) * APAD + q * 8];
#pragma unroll
        for (int tn = 0; tn < 4; ++tn) {
            int row = wn + tn * 16 + l15;
            int slot = row * 4 + (q ^ ((row >> 1) & 3));
            bfr[tn] = *(const bf16x8*)&lds_b[slot * 8];
        }
#pragma unroll
        for (int tm = 0; tm < 4; ++tm)
#pragma unroll
            for (int tn = 0; tn < 4; ++tn)
                acc[tm][tn] = __builtin_amdgcn_mfma_f32_16x16x32_bf16(
                    af[tm], bfr[tn], acc[tm][tn], 0, 0, 0);
    }

    // ---- epilogue: atomic-accumulate fp32 partials (softplus deferred) ----
#pragma unroll
    for (int tn = 0; tn < 4; ++tn) {
        int n = n0 + wn + tn * 16 + l15;
        if (n >= NOUT) continue;
#pragma unroll
        for (int tm = 0; tm < 4; ++tm) {
            int mbase = m0 + wm + tm * 16 + q * 4;
#pragma unroll
            for (int r = 0; r < 4; ++r)
                atomicAdd(&accbuf[(size_t)(mbase + r) * NOUT + n], acc[tm][tn][r]);
        }
    }
}

// ---------------- finalize: softplus on sigma region, copy to out ------------------
__global__ __launch_bounds__(256) void finalize(const float* __restrict__ accbuf,
                                                float* __restrict__ out) {
    size_t f = ((size_t)blockIdx.x * 256 + threadIdx.x) * 4;  // NOUT%4==0: same row
    int col = (int)(f % NOUT);
    float4 v = *(const float4*)(accbuf + f);
    float r[4] = {v.x, v.y, v.z, v.w};
#pragma unroll
    for (int j = 0; j < 4; ++j) {
        if (col + j >= 528) {
            float vv = r[j];
            float sp = (vv > 15.0f) ? vv : log1pf(expf(vv));
            r[j] = sp + 1e-7f;
        }
    }
    *(float4*)(out + f) = make_float4(r[0], r[1], r[2], r[3]);
}

extern "C" void kernel_launch(void* const* d_in, const int* in_sizes, int n_in,
                              void* d_out, int out_size, void* d_ws, size_t ws_size,
                              hipStream_t stream) {
    const float* x    = (const float*)d_in[0];
    const float* g    = (const float*)d_in[1];
    const float* Wmu  = (const float*)d_in[2];
    const float* bmu  = (const float*)d_in[3];
    const float* Wsig = (const float*)d_in[4];
    const float* bsig = (const float*)d_in[5];
    const float* Wpi  = (const float*)d_in[6];
    const float* bpi  = (const float*)d_in[7];
    float* out = (float*)d_out;

    unsigned short* Wt = (unsigned short*)d_ws;          // NPAD*KTOT*2 = 37.82 MB
    float* accbuf = (float*)((char*)d_ws + (size_t)NPAD * KTOT * 2);  // B*NOUT*4 = 34.08 MB

    hipMemsetAsync(accbuf, 0, (size_t)BATCH * NOUT * sizeof(float), stream);
    prep_wt<<<dim3(KTOT / 8, 5), 256, 0, stream>>>(Wmu, bmu, Wsig, bsig, Wpi, bpi, Wt);
    gemm_gmm<<<dim3(BATCH / 128, NPAD / 128, NSPLIT), 256, 0, stream>>>(x, g, Wt, accbuf);
    finalize<<<(BATCH * NOUT / 4 + 255) / 256, 256, 0, stream>>>(accbuf, out);
}